// Round 3
// baseline (122.710 us; speedup 1.0000x reference)
//
#include <hip/hip_runtime.h>
#include <math.h>

#define NROWS 8192
#define DIM 64
#define KNBR 200
#define BN_EPS 1e-5f
#define BIGF 3.402823466e38f

// ---------- wave-level helpers (wave = 64 lanes) ----------

// out_j (j = lane) = sum_{i<64} xlds[i] * W[i*64 + j]
__device__ __forceinline__ float matvec64(const float* xlds,
                                          const float* __restrict__ W,
                                          int lane) {
    float acc = 0.f;
#pragma unroll
    for (int i4 = 0; i4 < 16; ++i4) {
        float4 xv = *(const float4*)(xlds + i4 * 4);
        acc = fmaf(xv.x, W[(i4 * 4 + 0) * 64 + lane], acc);
        acc = fmaf(xv.y, W[(i4 * 4 + 1) * 64 + lane], acc);
        acc = fmaf(xv.z, W[(i4 * 4 + 2) * 64 + lane], acc);
        acc = fmaf(xv.w, W[(i4 * 4 + 3) * 64 + lane], acc);
    }
    return acc;
}

// out_j (j = lane) = sum_{i<128} xlds[i] * W[i*64 + j]
__device__ __forceinline__ float matvec128(const float* xlds,
                                           const float* __restrict__ W,
                                           int lane) {
    float acc = 0.f;
#pragma unroll
    for (int i4 = 0; i4 < 32; ++i4) {
        float4 xv = *(const float4*)(xlds + i4 * 4);
        acc = fmaf(xv.x, W[(i4 * 4 + 0) * 64 + lane], acc);
        acc = fmaf(xv.y, W[(i4 * 4 + 1) * 64 + lane], acc);
        acc = fmaf(xv.z, W[(i4 * 4 + 2) * 64 + lane], acc);
        acc = fmaf(xv.w, W[(i4 * 4 + 3) * 64 + lane], acc);
    }
    return acc;
}

__device__ __forceinline__ float d2part(const float4 a, const float4 b) {
    const float dx = a.x - b.x, dy = a.y - b.y, dz = a.z - b.z, dw = a.w - b.w;
    float d2 = dx * dx;
    d2 = fmaf(dy, dy, d2);
    d2 = fmaf(dz, dz, d2);
    d2 = fmaf(dw, dw, d2);
    return d2;
}

__device__ __forceinline__ float sum16(float v) {
    v += __shfl_xor(v, 1);
    v += __shfl_xor(v, 2);
    v += __shfl_xor(v, 4);
    v += __shfl_xor(v, 8);
    return v;
}

// ---------- fused kernel: 8 waves, 8 rows per block ----------
// Gather: wave w handles neighbor slots k == w (mod 8) of ALL 8 rows
// (identical trip counts for every wave in the block -> no intra-block
// imbalance). MLP: wave w handles row w.
__global__ __launch_bounds__(512, 8) void fused_rows(
    const float* __restrict__ v_embed,
    const float* __restrict__ u1p, const float* __restrict__ u2p,
    const float* __restrict__ u3p, const float* __restrict__ u4p,
    const float* __restrict__ evp,
    const float* __restrict__ w_ur1, const float* __restrict__ b_ur1,
    const float* __restrict__ w_ur2, const float* __restrict__ b_ur2,
    const float* __restrict__ w_vr1, const float* __restrict__ b_vr1,
    const float* __restrict__ w_vr2, const float* __restrict__ b_vr2,
    const float* __restrict__ w_uv1, const float* __restrict__ b_uv1,
    const float* __restrict__ w_uv2, const float* __restrict__ b_uv2,
    const float* __restrict__ w_uv3, const float* __restrict__ b_uv3,
    const float* __restrict__ bn1_g, const float* __restrict__ bn1_b,
    const float* __restrict__ bn1_m, const float* __restrict__ bn1_v,
    const float* __restrict__ bn2_g, const float* __restrict__ bn2_b,
    const float* __restrict__ bn2_m, const float* __restrict__ bn2_v,
    const float* __restrict__ bn3_g, const float* __restrict__ bn3_b,
    const float* __restrict__ bn3_m, const float* __restrict__ bn3_v,
    const float* __restrict__ bn4_g, const float* __restrict__ bn4_b,
    const float* __restrict__ bn4_m, const float* __restrict__ bn4_v,
    const int* __restrict__ nodes_v, const int* __restrict__ nbr_idx,
    const int* __restrict__ nbr_len,
    float* __restrict__ out_score, float* __restrict__ ws_d2,
    float* __restrict__ ws_c) {
    const int w = threadIdx.x >> 6;     // wave 0..7
    const int lane = threadIdx.x & 63;
    const int row0 = blockIdx.x * 8;
    const int myrow = row0 + w;

    __shared__ float xbuf[8][132];
    __shared__ float pmins[8][9];       // [row][wave], padded

    const int l16 = lane & 15;
    const int g = lane >> 4;            // 16-lane group 0..3

    // ================= gather phase: mod-8 slot interleave =================
    // Wave w's slots for a row: k = w + 8*s, s = 0..31 (covers k < 200).
    // Sub-batch j covers s in [8j, 8j+8); guard is wave-uniform.
#pragma unroll 2
    for (int r = 0; r < 8; ++r) {
        const int row = row0 + r;
        const int node = nodes_v[row];
        const float4 vq = ((const float4*)(v_embed + ((size_t)node << 6)))[l16];
        int len = nbr_len[row];
        if (len < 1) len = 1;
        const int* nb = nbr_idx + (size_t)row * KNBR;
        float dmin2 = BIGF;
#pragma unroll
        for (int j = 0; j < 4; ++j) {
            if (len > w + 64 * j) {     // wave-uniform guard
                const int sA = 8 * j + g;
                const int sB = 8 * j + 4 + g;
                const int kA = w + 8 * sA;
                const int kB = w + 8 * sB;
                const int kAc = kA < len ? kA : (len - 1);
                const int kBc = kB < len ? kB : (len - 1);
                const int iA = nb[kAc];
                const int iB = nb[kBc];
                const float4 nA = ((const float4*)(v_embed + ((size_t)iA << 6)))[l16];
                const float4 nB = ((const float4*)(v_embed + ((size_t)iB << 6)))[l16];
                const float dA = sum16(d2part(vq, nA));
                const float dB = sum16(d2part(vq, nB));
                dmin2 = fminf(dmin2, kA < len ? dA : BIGF);
                dmin2 = fminf(dmin2, kB < len ? dB : BIGF);
            }
        }
        dmin2 = fminf(dmin2, __shfl_xor(dmin2, 16));
        dmin2 = fminf(dmin2, __shfl_xor(dmin2, 32));
        if (lane == 0) pmins[r][w] = dmin2;
    }

    // ================= MLP phase: wave w -> row myrow =================
    float* xw = xbuf[w];
    const size_t rb = (size_t)myrow * DIM + lane;
    const float u1 = u1p[rb], u2 = u2p[rb], u3 = u3p[rb], u4 = u4p[rb];
    const float ev = evp[rb];

    float d12 = u1 - u2, d23 = u2 - u3, d34 = u3 - u4;
    float s1 = d12 * d12, s2 = d23 * d23, s3 = d34 * d34;
#pragma unroll
    for (int m = 1; m < 64; m <<= 1) {
        s1 += __shfl_xor(s1, m);
        s2 += __shfl_xor(s2, m);
        s3 += __shfl_xor(s3, m);
    }
    const float cval = (sqrtf(s1) + sqrtf(s2) + sqrtf(s3)) * (1.0f / 3.0f);

    float eu = u1 * 0.032058603280084993f;
    eu = fmaf(u2, 0.087144318742032567f, eu);
    eu = fmaf(u3, 0.236882818089910134f, eu);
    eu = fmaf(u4, 0.643914259887972245f, eu);

    xw[lane] = eu;
    float t1 = matvec64(xw, w_ur1, lane) + b_ur1[lane];
    t1 = (t1 - bn1_m[lane]) * rsqrtf(bn1_v[lane] + BN_EPS) * bn1_g[lane] + bn1_b[lane];
    t1 = fmaxf(t1, 0.f);
    xw[lane] = t1;
    const float xu = matvec64(xw, w_ur2, lane) + b_ur2[lane];
    xw[lane] = ev;
    float t2 = matvec64(xw, w_vr1, lane) + b_vr1[lane];
    t2 = (t2 - bn2_m[lane]) * rsqrtf(bn2_v[lane] + BN_EPS) * bn2_g[lane] + bn2_b[lane];
    t2 = fmaxf(t2, 0.f);
    xw[lane] = t2;
    const float xv = matvec64(xw, w_vr2, lane) + b_vr2[lane];
    xw[lane] = xu;
    xw[64 + lane] = xv;
    float t3 = matvec128(xw, w_uv1, lane) + b_uv1[lane];
    t3 = (t3 - bn3_m[lane]) * rsqrtf(bn3_v[lane] + BN_EPS) * bn3_g[lane] + bn3_b[lane];
    t3 = fmaxf(t3, 0.f);
    xw[lane] = t3;
    const int jj = lane & 15;
    const int q = lane >> 4;
    float h4 = 0.f;
#pragma unroll
    for (int i = 0; i < 16; ++i) {
        h4 = fmaf(xw[q * 16 + i], w_uv2[(q * 16 + i) * 16 + jj], h4);
    }
    h4 += __shfl_xor(h4, 16);
    h4 += __shfl_xor(h4, 32);
    h4 += b_uv2[jj];
    h4 = (h4 - bn4_m[jj]) * rsqrtf(bn4_v[jj] + BN_EPS) * bn4_g[jj] + bn4_b[jj];
    h4 = fmaxf(h4, 0.f);
    float p = h4 * w_uv3[jj];
#pragma unroll
    for (int m = 1; m < 16; m <<= 1) p += __shfl_xor(p, m);
    const float score = p + b_uv3[0];

    if (lane == 0) {
        out_score[myrow] = score;
        ws_c[myrow] = cval;
    }

    // ================= cross-wave min reduce =================
    __syncthreads();
    if (w == 0) {
        const int r = lane >> 3;        // row 0..7
        float v = pmins[r][lane & 7];
        v = fminf(v, __shfl_xor(v, 1));
        v = fminf(v, __shfl_xor(v, 2));
        v = fminf(v, __shfl_xor(v, 4));
        if ((lane & 7) == 0) ws_d2[row0 + r] = v;
    }
}

// ---------- final combine: single block does global min/max + outputs ----------
__global__ __launch_bounds__(1024) void combine(
    const float* __restrict__ ws_d2, const float* __restrict__ ws_c,
    float* __restrict__ out) {
    const int tid = threadIdx.x;
    __shared__ float red[4][16];

    float ld2[8], lc[8];
    float dmin = BIGF, dmax = -BIGF, cmin = BIGF, cmax = -BIGF;
#pragma unroll
    for (int i = 0; i < 8; ++i) {
        const int b = tid * 8 + i;  // 1024 * 8 == 8192
        ld2[i] = ws_d2[b];
        lc[i] = ws_c[b];
        dmin = fminf(dmin, ld2[i]);
        dmax = fmaxf(dmax, ld2[i]);
        cmin = fminf(cmin, lc[i]);
        cmax = fmaxf(cmax, lc[i]);
    }
#pragma unroll
    for (int m = 1; m < 64; m <<= 1) {
        dmin = fminf(dmin, __shfl_xor(dmin, m));
        dmax = fmaxf(dmax, __shfl_xor(dmax, m));
        cmin = fminf(cmin, __shfl_xor(cmin, m));
        cmax = fmaxf(cmax, __shfl_xor(cmax, m));
    }
    const int wid = tid >> 6;
    const int lane = tid & 63;
    if (lane == 0) {
        red[0][wid] = dmin;
        red[1][wid] = dmax;
        red[2][wid] = cmin;
        red[3][wid] = cmax;
    }
    __syncthreads();
    dmin = red[0][0]; dmax = red[1][0]; cmin = red[2][0]; cmax = red[3][0];
#pragma unroll
    for (int i = 1; i < 16; ++i) {
        dmin = fminf(dmin, red[0][i]);
        dmax = fmaxf(dmax, red[1][i]);
        cmin = fminf(cmin, red[2][i]);
        cmax = fmaxf(cmax, red[3][i]);
    }
    const float dlo = sqrtf(dmin);
    const float dhi = sqrtf(dmax);
    const float inv_d = 1.f / (dhi - dlo);
    const float inv_c = 1.f / (cmax - cmin);
#pragma unroll
    for (int i = 0; i < 8; ++i) {
        const int b = tid * 8 + i;
        const float t = (sqrtf(ld2[i]) - dlo) * inv_d;
        const float unexp = 6.f * t * expf(-6.f * t);
        out[b] += unexp * (lc[i] - cmin) * inv_c;
    }
}

extern "C" void kernel_launch(void* const* d_in, const int* in_sizes, int n_in,
                              void* d_out, int out_size, void* d_ws, size_t ws_size,
                              hipStream_t stream) {
    const float* v_embed = (const float*)d_in[0];
    const float* u1 = (const float*)d_in[1];
    const float* u2 = (const float*)d_in[2];
    const float* u3 = (const float*)d_in[3];
    const float* u4 = (const float*)d_in[4];
    const float* ev = (const float*)d_in[5];
    const float* w_ur1 = (const float*)d_in[6];
    const float* b_ur1 = (const float*)d_in[7];
    const float* w_ur2 = (const float*)d_in[8];
    const float* b_ur2 = (const float*)d_in[9];
    const float* w_vr1 = (const float*)d_in[10];
    const float* b_vr1 = (const float*)d_in[11];
    const float* w_vr2 = (const float*)d_in[12];
    const float* b_vr2 = (const float*)d_in[13];
    const float* w_uv1 = (const float*)d_in[14];
    const float* b_uv1 = (const float*)d_in[15];
    const float* w_uv2 = (const float*)d_in[16];
    const float* b_uv2 = (const float*)d_in[17];
    const float* w_uv3 = (const float*)d_in[18];
    const float* b_uv3 = (const float*)d_in[19];
    const int* nodes_v = (const int*)d_in[20];
    const int* nbr_idx = (const int*)d_in[21];
    const int* nbr_len = (const int*)d_in[22];
    const float* bn1_g = (const float*)d_in[23];
    const float* bn1_b = (const float*)d_in[24];
    const float* bn1_m = (const float*)d_in[25];
    const float* bn1_v = (const float*)d_in[26];
    const float* bn2_g = (const float*)d_in[27];
    const float* bn2_b = (const float*)d_in[28];
    const float* bn2_m = (const float*)d_in[29];
    const float* bn2_v = (const float*)d_in[30];
    const float* bn3_g = (const float*)d_in[31];
    const float* bn3_b = (const float*)d_in[32];
    const float* bn3_m = (const float*)d_in[33];
    const float* bn3_v = (const float*)d_in[34];
    const float* bn4_g = (const float*)d_in[35];
    const float* bn4_b = (const float*)d_in[36];
    const float* bn4_m = (const float*)d_in[37];
    const float* bn4_v = (const float*)d_in[38];

    float* out = (float*)d_out;
    float* wsf = (float*)d_ws;
    float* ws_d2 = wsf;
    float* ws_c = wsf + NROWS;

    hipLaunchKernelGGL(fused_rows, dim3(NROWS / 8), dim3(512), 0, stream,
                       v_embed, u1, u2, u3, u4, ev,
                       w_ur1, b_ur1, w_ur2, b_ur2, w_vr1, b_vr1, w_vr2, b_vr2,
                       w_uv1, b_uv1, w_uv2, b_uv2, w_uv3, b_uv3,
                       bn1_g, bn1_b, bn1_m, bn1_v,
                       bn2_g, bn2_b, bn2_m, bn2_v,
                       bn3_g, bn3_b, bn3_m, bn3_v,
                       bn4_g, bn4_b, bn4_m, bn4_v,
                       nodes_v, nbr_idx, nbr_len,
                       out, ws_d2, ws_c);
    hipLaunchKernelGGL(combine, dim3(1), dim3(1024), 0, stream,
                       ws_d2, ws_c, out);
}

// Round 4
// 87.537 us; speedup vs baseline: 1.4018x; 1.4018x over previous
//
#include <hip/hip_runtime.h>
#include <math.h>

#define NROWS 8192
#define DIM 64
#define KNBR 200
#define NCHUNK 7            // ceil(200/32) chunks of 32 neighbors
#define BN_EPS 1e-5f
#define BIGF 3.402823466e38f

// ---------- wave-level helpers (wave = 64 lanes) ----------

__device__ __forceinline__ float matvec64(const float* xlds,
                                          const float* __restrict__ W,
                                          int lane) {
    float acc = 0.f;
#pragma unroll
    for (int i4 = 0; i4 < 16; ++i4) {
        float4 xv = *(const float4*)(xlds + i4 * 4);
        acc = fmaf(xv.x, W[(i4 * 4 + 0) * 64 + lane], acc);
        acc = fmaf(xv.y, W[(i4 * 4 + 1) * 64 + lane], acc);
        acc = fmaf(xv.z, W[(i4 * 4 + 2) * 64 + lane], acc);
        acc = fmaf(xv.w, W[(i4 * 4 + 3) * 64 + lane], acc);
    }
    return acc;
}

__device__ __forceinline__ float matvec128(const float* xlds,
                                           const float* __restrict__ W,
                                           int lane) {
    float acc = 0.f;
#pragma unroll
    for (int i4 = 0; i4 < 32; ++i4) {
        float4 xv = *(const float4*)(xlds + i4 * 4);
        acc = fmaf(xv.x, W[(i4 * 4 + 0) * 64 + lane], acc);
        acc = fmaf(xv.y, W[(i4 * 4 + 1) * 64 + lane], acc);
        acc = fmaf(xv.z, W[(i4 * 4 + 2) * 64 + lane], acc);
        acc = fmaf(xv.w, W[(i4 * 4 + 3) * 64 + lane], acc);
    }
    return acc;
}

__device__ __forceinline__ float d2part(const float4 a, const float4 b) {
    const float dx = a.x - b.x, dy = a.y - b.y, dz = a.z - b.z, dw = a.w - b.w;
    float d2 = dx * dx;
    d2 = fmaf(dy, dy, d2);
    d2 = fmaf(dz, dz, d2);
    d2 = fmaf(dw, dw, d2);
    return d2;
}

__device__ __forceinline__ float sum16(float v) {
    v += __shfl_xor(v, 1);
    v += __shfl_xor(v, 2);
    v += __shfl_xor(v, 4);
    v += __shfl_xor(v, 8);
    return v;
}

// ---------- fused heterogeneous kernel ----------
// grid = (NROWS/4, 8). blockIdx.y < 7: gather chunk y (32 neighbors) for
// 4 rows (one wave each); blockIdx.y == 7: MLP + curiosity for 4 rows.
// No atomics; gather waves write partial mins to part[row*7+chunk].
__global__ __launch_bounds__(256) void fused_main(
    const float* __restrict__ v_embed,
    const float* __restrict__ u1p, const float* __restrict__ u2p,
    const float* __restrict__ u3p, const float* __restrict__ u4p,
    const float* __restrict__ evp,
    const float* __restrict__ w_ur1, const float* __restrict__ b_ur1,
    const float* __restrict__ w_ur2, const float* __restrict__ b_ur2,
    const float* __restrict__ w_vr1, const float* __restrict__ b_vr1,
    const float* __restrict__ w_vr2, const float* __restrict__ b_vr2,
    const float* __restrict__ w_uv1, const float* __restrict__ b_uv1,
    const float* __restrict__ w_uv2, const float* __restrict__ b_uv2,
    const float* __restrict__ w_uv3, const float* __restrict__ b_uv3,
    const float* __restrict__ bn1_g, const float* __restrict__ bn1_b,
    const float* __restrict__ bn1_m, const float* __restrict__ bn1_v,
    const float* __restrict__ bn2_g, const float* __restrict__ bn2_b,
    const float* __restrict__ bn2_m, const float* __restrict__ bn2_v,
    const float* __restrict__ bn3_g, const float* __restrict__ bn3_b,
    const float* __restrict__ bn3_m, const float* __restrict__ bn3_v,
    const float* __restrict__ bn4_g, const float* __restrict__ bn4_b,
    const float* __restrict__ bn4_m, const float* __restrict__ bn4_v,
    const int* __restrict__ nodes_v, const int* __restrict__ nbr_idx,
    const int* __restrict__ nbr_len,
    float* __restrict__ out_score, float* __restrict__ part,
    float* __restrict__ ws_c) {
    const int w = threadIdx.x >> 6;
    const int lane = threadIdx.x & 63;
    const int row = blockIdx.x * 4 + w;
    const int phase = blockIdx.y;

    __shared__ float xbuf[4][132];

    if (phase < NCHUNK) {
        // ================= gather: chunk `phase` of row =================
        int len = nbr_len[row];
        if (len < 1) len = 1;
        const int k0 = phase * 32;
        if (k0 >= len) return;          // wave-uniform early exit

        const int l16 = lane & 15;
        const int g = lane >> 4;        // 16-lane group: neighbor slot within 4
        const int node = nodes_v[row];
        const float4 vq = ((const float4*)(v_embed + ((size_t)node << 6)))[l16];
        const int* nb = nbr_idx + (size_t)row * KNBR;
        float dmin2 = BIGF;

        // first 16 slots: k = k0 + {g, 4+g, 8+g, 12+g}
        {
            const int ka = k0 + g, kb = k0 + 4 + g, kc = k0 + 8 + g, kd = k0 + 12 + g;
            const bool va = ka < len, vb = kb < len, vc = kc < len, vd = kd < len;
            const int ia = nb[va ? ka : 0];
            const int ib = nb[vb ? kb : 0];
            const int ic = nb[vc ? kc : 0];
            const int id = nb[vd ? kd : 0];
            const float4 na = ((const float4*)(v_embed + ((size_t)ia << 6)))[l16];
            const float4 nbv = ((const float4*)(v_embed + ((size_t)ib << 6)))[l16];
            const float4 nc = ((const float4*)(v_embed + ((size_t)ic << 6)))[l16];
            const float4 nd = ((const float4*)(v_embed + ((size_t)id << 6)))[l16];
            const float da = sum16(d2part(vq, na));
            const float db = sum16(d2part(vq, nbv));
            const float dc = sum16(d2part(vq, nc));
            const float dd = sum16(d2part(vq, nd));
            dmin2 = fminf(dmin2, va ? da : BIGF);
            dmin2 = fminf(dmin2, vb ? db : BIGF);
            dmin2 = fminf(dmin2, vc ? dc : BIGF);
            dmin2 = fminf(dmin2, vd ? dd : BIGF);
        }
        // second 16 slots (wave-uniform guard)
        if (k0 + 16 < len) {
            const int k1 = k0 + 16;
            const int ka = k1 + g, kb = k1 + 4 + g, kc = k1 + 8 + g, kd = k1 + 12 + g;
            const bool va = ka < len, vb = kb < len, vc = kc < len, vd = kd < len;
            const int ia = nb[va ? ka : 0];
            const int ib = nb[vb ? kb : 0];
            const int ic = nb[vc ? kc : 0];
            const int id = nb[vd ? kd : 0];
            const float4 na = ((const float4*)(v_embed + ((size_t)ia << 6)))[l16];
            const float4 nbv = ((const float4*)(v_embed + ((size_t)ib << 6)))[l16];
            const float4 nc = ((const float4*)(v_embed + ((size_t)ic << 6)))[l16];
            const float4 nd = ((const float4*)(v_embed + ((size_t)id << 6)))[l16];
            const float da = sum16(d2part(vq, na));
            const float db = sum16(d2part(vq, nbv));
            const float dc = sum16(d2part(vq, nc));
            const float dd = sum16(d2part(vq, nd));
            dmin2 = fminf(dmin2, va ? da : BIGF);
            dmin2 = fminf(dmin2, vb ? db : BIGF);
            dmin2 = fminf(dmin2, vc ? dc : BIGF);
            dmin2 = fminf(dmin2, vd ? dd : BIGF);
        }
        dmin2 = fminf(dmin2, __shfl_xor(dmin2, 16));
        dmin2 = fminf(dmin2, __shfl_xor(dmin2, 32));
        if (lane == 0) part[row * NCHUNK + phase] = dmin2;
        return;
    }

    // ================= MLP + curiosity: one wave per row =================
    float* xw = xbuf[w];
    const size_t rb = (size_t)row * DIM + lane;
    const float u1 = u1p[rb], u2 = u2p[rb], u3 = u3p[rb], u4 = u4p[rb];
    const float ev = evp[rb];

    float d12 = u1 - u2, d23 = u2 - u3, d34 = u3 - u4;
    float s1 = d12 * d12, s2 = d23 * d23, s3 = d34 * d34;
#pragma unroll
    for (int m = 1; m < 64; m <<= 1) {
        s1 += __shfl_xor(s1, m);
        s2 += __shfl_xor(s2, m);
        s3 += __shfl_xor(s3, m);
    }
    const float cval = (sqrtf(s1) + sqrtf(s2) + sqrtf(s3)) * (1.0f / 3.0f);

    float eu = u1 * 0.032058603280084993f;
    eu = fmaf(u2, 0.087144318742032567f, eu);
    eu = fmaf(u3, 0.236882818089910134f, eu);
    eu = fmaf(u4, 0.643914259887972245f, eu);

    xw[lane] = eu;
    float t1 = matvec64(xw, w_ur1, lane) + b_ur1[lane];
    t1 = (t1 - bn1_m[lane]) * rsqrtf(bn1_v[lane] + BN_EPS) * bn1_g[lane] + bn1_b[lane];
    t1 = fmaxf(t1, 0.f);
    xw[lane] = t1;
    const float xu = matvec64(xw, w_ur2, lane) + b_ur2[lane];
    xw[lane] = ev;
    float t2 = matvec64(xw, w_vr1, lane) + b_vr1[lane];
    t2 = (t2 - bn2_m[lane]) * rsqrtf(bn2_v[lane] + BN_EPS) * bn2_g[lane] + bn2_b[lane];
    t2 = fmaxf(t2, 0.f);
    xw[lane] = t2;
    const float xv = matvec64(xw, w_vr2, lane) + b_vr2[lane];
    xw[lane] = xu;
    xw[64 + lane] = xv;
    float t3 = matvec128(xw, w_uv1, lane) + b_uv1[lane];
    t3 = (t3 - bn3_m[lane]) * rsqrtf(bn3_v[lane] + BN_EPS) * bn3_g[lane] + bn3_b[lane];
    t3 = fmaxf(t3, 0.f);
    xw[lane] = t3;
    const int jj = lane & 15;
    const int q = lane >> 4;
    float h4 = 0.f;
#pragma unroll
    for (int i = 0; i < 16; ++i) {
        h4 = fmaf(xw[q * 16 + i], w_uv2[(q * 16 + i) * 16 + jj], h4);
    }
    h4 += __shfl_xor(h4, 16);
    h4 += __shfl_xor(h4, 32);
    h4 += b_uv2[jj];
    h4 = (h4 - bn4_m[jj]) * rsqrtf(bn4_v[jj] + BN_EPS) * bn4_g[jj] + bn4_b[jj];
    h4 = fmaxf(h4, 0.f);
    float p = h4 * w_uv3[jj];
#pragma unroll
    for (int m = 1; m < 16; m <<= 1) p += __shfl_xor(p, m);
    const float score = p + b_uv3[0];

    if (lane == 0) {
        out_score[row] = score;
        ws_c[row] = cval;
    }
}

// ---------- final combine: reduce partials + global min/max + outputs ----------
__global__ __launch_bounds__(1024) void combine(
    const float* __restrict__ part, const float* __restrict__ ws_c,
    const int* __restrict__ nbr_len, float* __restrict__ out) {
    const int tid = threadIdx.x;
    __shared__ float red[4][16];

    float ld2[8], lc[8];
    float dmin = BIGF, dmax = -BIGF, cmin = BIGF, cmax = -BIGF;
#pragma unroll
    for (int i = 0; i < 8; ++i) {
        const int b = tid * 8 + i;  // 1024 * 8 == 8192
        int len = nbr_len[b];
        if (len < 1) len = 1;
        const int nch = (len + 31) >> 5;
        float m = part[b * NCHUNK];
        for (int c = 1; c < nch; ++c) m = fminf(m, part[b * NCHUNK + c]);
        ld2[i] = m;
        lc[i] = ws_c[b];
        dmin = fminf(dmin, m);
        dmax = fmaxf(dmax, m);
        cmin = fminf(cmin, lc[i]);
        cmax = fmaxf(cmax, lc[i]);
    }
#pragma unroll
    for (int m = 1; m < 64; m <<= 1) {
        dmin = fminf(dmin, __shfl_xor(dmin, m));
        dmax = fmaxf(dmax, __shfl_xor(dmax, m));
        cmin = fminf(cmin, __shfl_xor(cmin, m));
        cmax = fmaxf(cmax, __shfl_xor(cmax, m));
    }
    const int wid = tid >> 6;
    const int lane = tid & 63;
    if (lane == 0) {
        red[0][wid] = dmin;
        red[1][wid] = dmax;
        red[2][wid] = cmin;
        red[3][wid] = cmax;
    }
    __syncthreads();
    dmin = red[0][0]; dmax = red[1][0]; cmin = red[2][0]; cmax = red[3][0];
#pragma unroll
    for (int i = 1; i < 16; ++i) {
        dmin = fminf(dmin, red[0][i]);
        dmax = fmaxf(dmax, red[1][i]);
        cmin = fminf(cmin, red[2][i]);
        cmax = fmaxf(cmax, red[3][i]);
    }
    const float dlo = sqrtf(dmin);
    const float dhi = sqrtf(dmax);
    const float inv_d = 1.f / (dhi - dlo);
    const float inv_c = 1.f / (cmax - cmin);
#pragma unroll
    for (int i = 0; i < 8; ++i) {
        const int b = tid * 8 + i;
        const float t = (sqrtf(ld2[i]) - dlo) * inv_d;
        const float unexp = 6.f * t * expf(-6.f * t);
        out[b] += unexp * (lc[i] - cmin) * inv_c;
    }
}

extern "C" void kernel_launch(void* const* d_in, const int* in_sizes, int n_in,
                              void* d_out, int out_size, void* d_ws, size_t ws_size,
                              hipStream_t stream) {
    const float* v_embed = (const float*)d_in[0];
    const float* u1 = (const float*)d_in[1];
    const float* u2 = (const float*)d_in[2];
    const float* u3 = (const float*)d_in[3];
    const float* u4 = (const float*)d_in[4];
    const float* ev = (const float*)d_in[5];
    const float* w_ur1 = (const float*)d_in[6];
    const float* b_ur1 = (const float*)d_in[7];
    const float* w_ur2 = (const float*)d_in[8];
    const float* b_ur2 = (const float*)d_in[9];
    const float* w_vr1 = (const float*)d_in[10];
    const float* b_vr1 = (const float*)d_in[11];
    const float* w_vr2 = (const float*)d_in[12];
    const float* b_vr2 = (const float*)d_in[13];
    const float* w_uv1 = (const float*)d_in[14];
    const float* b_uv1 = (const float*)d_in[15];
    const float* w_uv2 = (const float*)d_in[16];
    const float* b_uv2 = (const float*)d_in[17];
    const float* w_uv3 = (const float*)d_in[18];
    const float* b_uv3 = (const float*)d_in[19];
    const int* nodes_v = (const int*)d_in[20];
    const int* nbr_idx = (const int*)d_in[21];
    const int* nbr_len = (const int*)d_in[22];
    const float* bn1_g = (const float*)d_in[23];
    const float* bn1_b = (const float*)d_in[24];
    const float* bn1_m = (const float*)d_in[25];
    const float* bn1_v = (const float*)d_in[26];
    const float* bn2_g = (const float*)d_in[27];
    const float* bn2_b = (const float*)d_in[28];
    const float* bn2_m = (const float*)d_in[29];
    const float* bn2_v = (const float*)d_in[30];
    const float* bn3_g = (const float*)d_in[31];
    const float* bn3_b = (const float*)d_in[32];
    const float* bn3_m = (const float*)d_in[33];
    const float* bn3_v = (const float*)d_in[34];
    const float* bn4_g = (const float*)d_in[35];
    const float* bn4_b = (const float*)d_in[36];
    const float* bn4_m = (const float*)d_in[37];
    const float* bn4_v = (const float*)d_in[38];

    float* out = (float*)d_out;
    // workspace: part[NROWS*NCHUNK] then ws_c[NROWS]
    float* wsf = (float*)d_ws;
    float* part = wsf;
    float* ws_c = wsf + NROWS * NCHUNK;

    hipLaunchKernelGGL(fused_main, dim3(NROWS / 4, 8), dim3(256), 0, stream,
                       v_embed, u1, u2, u3, u4, ev,
                       w_ur1, b_ur1, w_ur2, b_ur2, w_vr1, b_vr1, w_vr2, b_vr2,
                       w_uv1, b_uv1, w_uv2, b_uv2, w_uv3, b_uv3,
                       bn1_g, bn1_b, bn1_m, bn1_v,
                       bn2_g, bn2_b, bn2_m, bn2_v,
                       bn3_g, bn3_b, bn3_m, bn3_v,
                       bn4_g, bn4_b, bn4_m, bn4_v,
                       nodes_v, nbr_idx, nbr_len,
                       out, part, ws_c);
    hipLaunchKernelGGL(combine, dim3(1), dim3(1024), 0, stream,
                       part, ws_c, nbr_len, out);
}

// Round 5
// 78.929 us; speedup vs baseline: 1.5547x; 1.1091x over previous
//
#include <hip/hip_runtime.h>
#include <math.h>

#define NROWS 8192
#define DIM 64
#define KNBR 200
#define BN_EPS 1e-5f
#define BIGF 3.402823466e38f

// ---------- wave-level helpers (wave = 64 lanes) ----------

__device__ __forceinline__ float matvec64(const float* xlds,
                                          const float* __restrict__ W,
                                          int lane) {
    float acc = 0.f;
#pragma unroll
    for (int i4 = 0; i4 < 16; ++i4) {
        float4 xv = *(const float4*)(xlds + i4 * 4);
        acc = fmaf(xv.x, W[(i4 * 4 + 0) * 64 + lane], acc);
        acc = fmaf(xv.y, W[(i4 * 4 + 1) * 64 + lane], acc);
        acc = fmaf(xv.z, W[(i4 * 4 + 2) * 64 + lane], acc);
        acc = fmaf(xv.w, W[(i4 * 4 + 3) * 64 + lane], acc);
    }
    return acc;
}

__device__ __forceinline__ float matvec128(const float* xlds,
                                           const float* __restrict__ W,
                                           int lane) {
    float acc = 0.f;
#pragma unroll
    for (int i4 = 0; i4 < 32; ++i4) {
        float4 xv = *(const float4*)(xlds + i4 * 4);
        acc = fmaf(xv.x, W[(i4 * 4 + 0) * 64 + lane], acc);
        acc = fmaf(xv.y, W[(i4 * 4 + 1) * 64 + lane], acc);
        acc = fmaf(xv.z, W[(i4 * 4 + 2) * 64 + lane], acc);
        acc = fmaf(xv.w, W[(i4 * 4 + 3) * 64 + lane], acc);
    }
    return acc;
}

// ---------- fused kernel: one wave per row, transposed gather ----------
// Gather: lane k owns neighbor (k0+lane) ENTIRELY -- 16 independent float4
// loads per neighbor, query broadcast from LDS, no cross-lane ops in the
// loop. Tail lanes clamp to nb[len-1]: duplicate valid distance, min-safe.
__global__ __launch_bounds__(256) void fused_rows(
    const float* __restrict__ v_embed,
    const float* __restrict__ u1p, const float* __restrict__ u2p,
    const float* __restrict__ u3p, const float* __restrict__ u4p,
    const float* __restrict__ evp,
    const float* __restrict__ w_ur1, const float* __restrict__ b_ur1,
    const float* __restrict__ w_ur2, const float* __restrict__ b_ur2,
    const float* __restrict__ w_vr1, const float* __restrict__ b_vr1,
    const float* __restrict__ w_vr2, const float* __restrict__ b_vr2,
    const float* __restrict__ w_uv1, const float* __restrict__ b_uv1,
    const float* __restrict__ w_uv2, const float* __restrict__ b_uv2,
    const float* __restrict__ w_uv3, const float* __restrict__ b_uv3,
    const float* __restrict__ bn1_g, const float* __restrict__ bn1_b,
    const float* __restrict__ bn1_m, const float* __restrict__ bn1_v,
    const float* __restrict__ bn2_g, const float* __restrict__ bn2_b,
    const float* __restrict__ bn2_m, const float* __restrict__ bn2_v,
    const float* __restrict__ bn3_g, const float* __restrict__ bn3_b,
    const float* __restrict__ bn3_m, const float* __restrict__ bn3_v,
    const float* __restrict__ bn4_g, const float* __restrict__ bn4_b,
    const float* __restrict__ bn4_m, const float* __restrict__ bn4_v,
    const int* __restrict__ nodes_v, const int* __restrict__ nbr_idx,
    const int* __restrict__ nbr_len,
    float* __restrict__ out_score, float* __restrict__ ws_d2,
    float* __restrict__ ws_c) {
    const int w = threadIdx.x >> 6;
    const int lane = threadIdx.x & 63;
    const int row = blockIdx.x * 4 + w;

    __shared__ float xbuf[4][132];
    __shared__ float qbuf[4][64];

    // ---- stage query row into LDS (one barrier, then broadcast reads) ----
    const int node = nodes_v[row];
    const float* vrow = v_embed + ((size_t)node << 6);
    if (lane < 16) {
        const float4 vq = ((const float4*)vrow)[lane];
        *(float4*)&qbuf[w][lane * 4] = vq;
    }
    __syncthreads();

    int len = nbr_len[row];
    if (len < 1) len = 1;
    const int* nb = nbr_idx + (size_t)row * KNBR;

    float dmin2 = BIGF;
    for (int k0 = 0; k0 < len; k0 += 64) {
        int k = k0 + lane;
        if (k >= len) k = len - 1;       // duplicate valid neighbor: min-safe
        const int idx = nb[k];
        const float4* np4 = (const float4*)(v_embed + ((size_t)idx << 6));
        float a0 = 0.f, a1 = 0.f, a2 = 0.f, a3 = 0.f;
#pragma unroll
        for (int d4 = 0; d4 < 16; d4 += 4) {
            const float4 n0 = np4[d4 + 0];
            const float4 n1 = np4[d4 + 1];
            const float4 n2 = np4[d4 + 2];
            const float4 n3 = np4[d4 + 3];
            const float4 q0 = *(const float4*)&qbuf[w][(d4 + 0) * 4];
            const float4 q1 = *(const float4*)&qbuf[w][(d4 + 1) * 4];
            const float4 q2 = *(const float4*)&qbuf[w][(d4 + 2) * 4];
            const float4 q3 = *(const float4*)&qbuf[w][(d4 + 3) * 4];
            float dx;
            dx = q0.x - n0.x; a0 = fmaf(dx, dx, a0);
            dx = q0.y - n0.y; a0 = fmaf(dx, dx, a0);
            dx = q0.z - n0.z; a0 = fmaf(dx, dx, a0);
            dx = q0.w - n0.w; a0 = fmaf(dx, dx, a0);
            dx = q1.x - n1.x; a1 = fmaf(dx, dx, a1);
            dx = q1.y - n1.y; a1 = fmaf(dx, dx, a1);
            dx = q1.z - n1.z; a1 = fmaf(dx, dx, a1);
            dx = q1.w - n1.w; a1 = fmaf(dx, dx, a1);
            dx = q2.x - n2.x; a2 = fmaf(dx, dx, a2);
            dx = q2.y - n2.y; a2 = fmaf(dx, dx, a2);
            dx = q2.z - n2.z; a2 = fmaf(dx, dx, a2);
            dx = q2.w - n2.w; a2 = fmaf(dx, dx, a2);
            dx = q3.x - n3.x; a3 = fmaf(dx, dx, a3);
            dx = q3.y - n3.y; a3 = fmaf(dx, dx, a3);
            dx = q3.z - n3.z; a3 = fmaf(dx, dx, a3);
            dx = q3.w - n3.w; a3 = fmaf(dx, dx, a3);
        }
        const float d2 = (a0 + a1) + (a2 + a3);
        dmin2 = fminf(dmin2, d2);
    }
    // single min-reduce per row
#pragma unroll
    for (int m = 1; m < 64; m <<= 1) dmin2 = fminf(dmin2, __shfl_xor(dmin2, m));

    // ================= MLP + curiosity =================
    float* xw = xbuf[w];
    const size_t rb = (size_t)row * DIM + lane;
    const float u1 = u1p[rb], u2 = u2p[rb], u3 = u3p[rb], u4 = u4p[rb];
    const float ev = evp[rb];

    float d12 = u1 - u2, d23 = u2 - u3, d34 = u3 - u4;
    float s1 = d12 * d12, s2 = d23 * d23, s3 = d34 * d34;
#pragma unroll
    for (int m = 1; m < 64; m <<= 1) {
        s1 += __shfl_xor(s1, m);
        s2 += __shfl_xor(s2, m);
        s3 += __shfl_xor(s3, m);
    }
    const float cval = (sqrtf(s1) + sqrtf(s2) + sqrtf(s3)) * (1.0f / 3.0f);

    float eu = u1 * 0.032058603280084993f;
    eu = fmaf(u2, 0.087144318742032567f, eu);
    eu = fmaf(u3, 0.236882818089910134f, eu);
    eu = fmaf(u4, 0.643914259887972245f, eu);

    xw[lane] = eu;
    float t1 = matvec64(xw, w_ur1, lane) + b_ur1[lane];
    t1 = (t1 - bn1_m[lane]) * rsqrtf(bn1_v[lane] + BN_EPS) * bn1_g[lane] + bn1_b[lane];
    t1 = fmaxf(t1, 0.f);
    xw[lane] = t1;
    const float xu = matvec64(xw, w_ur2, lane) + b_ur2[lane];
    xw[lane] = ev;
    float t2 = matvec64(xw, w_vr1, lane) + b_vr1[lane];
    t2 = (t2 - bn2_m[lane]) * rsqrtf(bn2_v[lane] + BN_EPS) * bn2_g[lane] + bn2_b[lane];
    t2 = fmaxf(t2, 0.f);
    xw[lane] = t2;
    const float xv = matvec64(xw, w_vr2, lane) + b_vr2[lane];
    xw[lane] = xu;
    xw[64 + lane] = xv;
    float t3 = matvec128(xw, w_uv1, lane) + b_uv1[lane];
    t3 = (t3 - bn3_m[lane]) * rsqrtf(bn3_v[lane] + BN_EPS) * bn3_g[lane] + bn3_b[lane];
    t3 = fmaxf(t3, 0.f);
    xw[lane] = t3;
    const int jj = lane & 15;
    const int q = lane >> 4;
    float h4 = 0.f;
#pragma unroll
    for (int i = 0; i < 16; ++i) {
        h4 = fmaf(xw[q * 16 + i], w_uv2[(q * 16 + i) * 16 + jj], h4);
    }
    h4 += __shfl_xor(h4, 16);
    h4 += __shfl_xor(h4, 32);
    h4 += b_uv2[jj];
    h4 = (h4 - bn4_m[jj]) * rsqrtf(bn4_v[jj] + BN_EPS) * bn4_g[jj] + bn4_b[jj];
    h4 = fmaxf(h4, 0.f);
    float p = h4 * w_uv3[jj];
#pragma unroll
    for (int m = 1; m < 16; m <<= 1) p += __shfl_xor(p, m);
    const float score = p + b_uv3[0];

    if (lane == 0) {
        out_score[row] = score;
        ws_d2[row] = dmin2;
        ws_c[row] = cval;
    }
}

// ---------- final combine: single block, global min/max + outputs ----------
__global__ __launch_bounds__(1024) void combine(
    const float* __restrict__ ws_d2, const float* __restrict__ ws_c,
    float* __restrict__ out) {
    const int tid = threadIdx.x;
    __shared__ float red[4][16];

    float ld2[8], lc[8];
    float dmin = BIGF, dmax = -BIGF, cmin = BIGF, cmax = -BIGF;
#pragma unroll
    for (int i = 0; i < 8; ++i) {
        const int b = tid * 8 + i;  // 1024 * 8 == 8192
        ld2[i] = ws_d2[b];
        lc[i] = ws_c[b];
        dmin = fminf(dmin, ld2[i]);
        dmax = fmaxf(dmax, ld2[i]);
        cmin = fminf(cmin, lc[i]);
        cmax = fmaxf(cmax, lc[i]);
    }
#pragma unroll
    for (int m = 1; m < 64; m <<= 1) {
        dmin = fminf(dmin, __shfl_xor(dmin, m));
        dmax = fmaxf(dmax, __shfl_xor(dmax, m));
        cmin = fminf(cmin, __shfl_xor(cmin, m));
        cmax = fmaxf(cmax, __shfl_xor(cmax, m));
    }
    const int wid = tid >> 6;
    const int lane = tid & 63;
    if (lane == 0) {
        red[0][wid] = dmin;
        red[1][wid] = dmax;
        red[2][wid] = cmin;
        red[3][wid] = cmax;
    }
    __syncthreads();
    dmin = red[0][0]; dmax = red[1][0]; cmin = red[2][0]; cmax = red[3][0];
#pragma unroll
    for (int i = 1; i < 16; ++i) {
        dmin = fminf(dmin, red[0][i]);
        dmax = fmaxf(dmax, red[1][i]);
        cmin = fminf(cmin, red[2][i]);
        cmax = fmaxf(cmax, red[3][i]);
    }
    const float dlo = sqrtf(dmin);
    const float dhi = sqrtf(dmax);
    const float inv_d = 1.f / (dhi - dlo);
    const float inv_c = 1.f / (cmax - cmin);
#pragma unroll
    for (int i = 0; i < 8; ++i) {
        const int b = tid * 8 + i;
        const float t = (sqrtf(ld2[i]) - dlo) * inv_d;
        const float unexp = 6.f * t * expf(-6.f * t);
        out[b] += unexp * (lc[i] - cmin) * inv_c;
    }
}

extern "C" void kernel_launch(void* const* d_in, const int* in_sizes, int n_in,
                              void* d_out, int out_size, void* d_ws, size_t ws_size,
                              hipStream_t stream) {
    const float* v_embed = (const float*)d_in[0];
    const float* u1 = (const float*)d_in[1];
    const float* u2 = (const float*)d_in[2];
    const float* u3 = (const float*)d_in[3];
    const float* u4 = (const float*)d_in[4];
    const float* ev = (const float*)d_in[5];
    const float* w_ur1 = (const float*)d_in[6];
    const float* b_ur1 = (const float*)d_in[7];
    const float* w_ur2 = (const float*)d_in[8];
    const float* b_ur2 = (const float*)d_in[9];
    const float* w_vr1 = (const float*)d_in[10];
    const float* b_vr1 = (const float*)d_in[11];
    const float* w_vr2 = (const float*)d_in[12];
    const float* b_vr2 = (const float*)d_in[13];
    const float* w_uv1 = (const float*)d_in[14];
    const float* b_uv1 = (const float*)d_in[15];
    const float* w_uv2 = (const float*)d_in[16];
    const float* b_uv2 = (const float*)d_in[17];
    const float* w_uv3 = (const float*)d_in[18];
    const float* b_uv3 = (const float*)d_in[19];
    const int* nodes_v = (const int*)d_in[20];
    const int* nbr_idx = (const int*)d_in[21];
    const int* nbr_len = (const int*)d_in[22];
    const float* bn1_g = (const float*)d_in[23];
    const float* bn1_b = (const float*)d_in[24];
    const float* bn1_m = (const float*)d_in[25];
    const float* bn1_v = (const float*)d_in[26];
    const float* bn2_g = (const float*)d_in[27];
    const float* bn2_b = (const float*)d_in[28];
    const float* bn2_m = (const float*)d_in[29];
    const float* bn2_v = (const float*)d_in[30];
    const float* bn3_g = (const float*)d_in[31];
    const float* bn3_b = (const float*)d_in[32];
    const float* bn3_m = (const float*)d_in[33];
    const float* bn3_v = (const float*)d_in[34];
    const float* bn4_g = (const float*)d_in[35];
    const float* bn4_b = (const float*)d_in[36];
    const float* bn4_m = (const float*)d_in[37];
    const float* bn4_v = (const float*)d_in[38];

    float* out = (float*)d_out;
    float* wsf = (float*)d_ws;
    float* ws_d2 = wsf;
    float* ws_c = wsf + NROWS;

    hipLaunchKernelGGL(fused_rows, dim3(NROWS / 4), dim3(256), 0, stream,
                       v_embed, u1, u2, u3, u4, ev,
                       w_ur1, b_ur1, w_ur2, b_ur2, w_vr1, b_vr1, w_vr2, b_vr2,
                       w_uv1, b_uv1, w_uv2, b_uv2, w_uv3, b_uv3,
                       bn1_g, bn1_b, bn1_m, bn1_v,
                       bn2_g, bn2_b, bn2_m, bn2_v,
                       bn3_g, bn3_b, bn3_m, bn3_v,
                       bn4_g, bn4_b, bn4_m, bn4_v,
                       nodes_v, nbr_idx, nbr_len,
                       out, ws_d2, ws_c);
    hipLaunchKernelGGL(combine, dim3(1), dim3(1024), 0, stream,
                       ws_d2, ws_c, out);
}

// Round 6
// 61.932 us; speedup vs baseline: 1.9814x; 1.2744x over previous
//
#include <hip/hip_runtime.h>
#include <math.h>

#define NROWS 8192
#define DIM 64
#define KNBR 200
#define BN_EPS 1e-5f
#define BIGF 3.402823466e38f

// ---------- wave-level helpers (wave = 64 lanes) ----------

__device__ __forceinline__ float matvec64(const float* xlds,
                                          const float* __restrict__ W,
                                          int lane) {
    float acc = 0.f;
#pragma unroll
    for (int i4 = 0; i4 < 16; ++i4) {
        float4 xv = *(const float4*)(xlds + i4 * 4);
        acc = fmaf(xv.x, W[(i4 * 4 + 0) * 64 + lane], acc);
        acc = fmaf(xv.y, W[(i4 * 4 + 1) * 64 + lane], acc);
        acc = fmaf(xv.z, W[(i4 * 4 + 2) * 64 + lane], acc);
        acc = fmaf(xv.w, W[(i4 * 4 + 3) * 64 + lane], acc);
    }
    return acc;
}

__device__ __forceinline__ float matvec128(const float* xlds,
                                           const float* __restrict__ W,
                                           int lane) {
    float acc = 0.f;
#pragma unroll
    for (int i4 = 0; i4 < 32; ++i4) {
        float4 xv = *(const float4*)(xlds + i4 * 4);
        acc = fmaf(xv.x, W[(i4 * 4 + 0) * 64 + lane], acc);
        acc = fmaf(xv.y, W[(i4 * 4 + 1) * 64 + lane], acc);
        acc = fmaf(xv.z, W[(i4 * 4 + 2) * 64 + lane], acc);
        acc = fmaf(xv.w, W[(i4 * 4 + 3) * 64 + lane], acc);
    }
    return acc;
}

__device__ __forceinline__ float d2part(const float4 a, const float4 b) {
    const float dx = a.x - b.x, dy = a.y - b.y, dz = a.z - b.z, dw = a.w - b.w;
    float d2 = dx * dx;
    d2 = fmaf(dy, dy, d2);
    d2 = fmaf(dz, dz, d2);
    d2 = fmaf(dw, dw, d2);
    return d2;
}

__device__ __forceinline__ float sum16(float v) {
    v += __shfl_xor(v, 1);
    v += __shfl_xor(v, 2);
    v += __shfl_xor(v, 4);
    v += __shfl_xor(v, 8);
    return v;
}

// ---------- fused kernel: one wave per row ----------
// Gather layout (TA-optimal): 16 lanes own one neighbor (4 lines/group,
// 16 lines per instruction). 32 neighbors in flight per iteration
// (8 gather instructions = 128 lines). Out-of-range slots CLAMP to the
// last valid neighbor -- a duplicated valid distance, min-safe -- so the
// inner loop has no masking logic at all.
__global__ __launch_bounds__(256) void fused_rows(
    const float* __restrict__ v_embed,
    const float* __restrict__ u1p, const float* __restrict__ u2p,
    const float* __restrict__ u3p, const float* __restrict__ u4p,
    const float* __restrict__ evp,
    const float* __restrict__ w_ur1, const float* __restrict__ b_ur1,
    const float* __restrict__ w_ur2, const float* __restrict__ b_ur2,
    const float* __restrict__ w_vr1, const float* __restrict__ b_vr1,
    const float* __restrict__ w_vr2, const float* __restrict__ b_vr2,
    const float* __restrict__ w_uv1, const float* __restrict__ b_uv1,
    const float* __restrict__ w_uv2, const float* __restrict__ b_uv2,
    const float* __restrict__ w_uv3, const float* __restrict__ b_uv3,
    const float* __restrict__ bn1_g, const float* __restrict__ bn1_b,
    const float* __restrict__ bn1_m, const float* __restrict__ bn1_v,
    const float* __restrict__ bn2_g, const float* __restrict__ bn2_b,
    const float* __restrict__ bn2_m, const float* __restrict__ bn2_v,
    const float* __restrict__ bn3_g, const float* __restrict__ bn3_b,
    const float* __restrict__ bn3_m, const float* __restrict__ bn3_v,
    const float* __restrict__ bn4_g, const float* __restrict__ bn4_b,
    const float* __restrict__ bn4_m, const float* __restrict__ bn4_v,
    const int* __restrict__ nodes_v, const int* __restrict__ nbr_idx,
    const int* __restrict__ nbr_len,
    float* __restrict__ out_score, float* __restrict__ ws_d2,
    float* __restrict__ ws_c) {
    const int w = threadIdx.x >> 6;
    const int lane = threadIdx.x & 63;
    const int row = blockIdx.x * 4 + w;

    __shared__ float xbuf[4][132];

    const int l16 = lane & 15;
    const int g = lane >> 4;            // group 0..3

    // ---- gather setup (issue these loads as early as possible) ----
    const int node = nodes_v[row];
    int len = nbr_len[row];
    if (len < 1) len = 1;
    const int lenm1 = len - 1;
    const float4 vq = ((const float4*)(v_embed + ((size_t)node << 6)))[l16];
    const int* nb = nbr_idx + (size_t)row * KNBR;

    float dmin2 = BIGF;
    for (int k0 = 0; k0 < len; k0 += 32) {
        // slot for group g, sub-batch j: k0 + 4*j + g, clamped
        int k[8];
#pragma unroll
        for (int j = 0; j < 8; ++j) {
            int kk = k0 + 4 * j + g;
            k[j] = kk < lenm1 ? kk : lenm1;
        }
        int idx[8];
#pragma unroll
        for (int j = 0; j < 8; ++j) idx[j] = nb[k[j]];
        float4 nv[8];
#pragma unroll
        for (int j = 0; j < 8; ++j) {
            nv[j] = ((const float4*)(v_embed + ((size_t)idx[j] << 6)))[l16];
        }
        float d[8];
#pragma unroll
        for (int j = 0; j < 8; ++j) d[j] = sum16(d2part(vq, nv[j]));
#pragma unroll
        for (int j = 0; j < 8; ++j) dmin2 = fminf(dmin2, d[j]);
    }
    dmin2 = fminf(dmin2, __shfl_xor(dmin2, 16));
    dmin2 = fminf(dmin2, __shfl_xor(dmin2, 32));

    // ================= MLP + curiosity =================
    float* xw = xbuf[w];
    const size_t rb = (size_t)row * DIM + lane;
    const float u1 = u1p[rb], u2 = u2p[rb], u3 = u3p[rb], u4 = u4p[rb];
    const float ev = evp[rb];

    float d12 = u1 - u2, d23 = u2 - u3, d34 = u3 - u4;
    float s1 = d12 * d12, s2 = d23 * d23, s3 = d34 * d34;
#pragma unroll
    for (int m = 1; m < 64; m <<= 1) {
        s1 += __shfl_xor(s1, m);
        s2 += __shfl_xor(s2, m);
        s3 += __shfl_xor(s3, m);
    }
    const float cval = (sqrtf(s1) + sqrtf(s2) + sqrtf(s3)) * (1.0f / 3.0f);

    float eu = u1 * 0.032058603280084993f;
    eu = fmaf(u2, 0.087144318742032567f, eu);
    eu = fmaf(u3, 0.236882818089910134f, eu);
    eu = fmaf(u4, 0.643914259887972245f, eu);

    xw[lane] = eu;
    float t1 = matvec64(xw, w_ur1, lane) + b_ur1[lane];
    t1 = (t1 - bn1_m[lane]) * rsqrtf(bn1_v[lane] + BN_EPS) * bn1_g[lane] + bn1_b[lane];
    t1 = fmaxf(t1, 0.f);
    xw[lane] = t1;
    const float xu = matvec64(xw, w_ur2, lane) + b_ur2[lane];
    xw[lane] = ev;
    float t2 = matvec64(xw, w_vr1, lane) + b_vr1[lane];
    t2 = (t2 - bn2_m[lane]) * rsqrtf(bn2_v[lane] + BN_EPS) * bn2_g[lane] + bn2_b[lane];
    t2 = fmaxf(t2, 0.f);
    xw[lane] = t2;
    const float xv = matvec64(xw, w_vr2, lane) + b_vr2[lane];
    xw[lane] = xu;
    xw[64 + lane] = xv;
    float t3 = matvec128(xw, w_uv1, lane) + b_uv1[lane];
    t3 = (t3 - bn3_m[lane]) * rsqrtf(bn3_v[lane] + BN_EPS) * bn3_g[lane] + bn3_b[lane];
    t3 = fmaxf(t3, 0.f);
    xw[lane] = t3;
    const int jj = lane & 15;
    const int q = lane >> 4;
    float h4 = 0.f;
#pragma unroll
    for (int i = 0; i < 16; ++i) {
        h4 = fmaf(xw[q * 16 + i], w_uv2[(q * 16 + i) * 16 + jj], h4);
    }
    h4 += __shfl_xor(h4, 16);
    h4 += __shfl_xor(h4, 32);
    h4 += b_uv2[jj];
    h4 = (h4 - bn4_m[jj]) * rsqrtf(bn4_v[jj] + BN_EPS) * bn4_g[jj] + bn4_b[jj];
    h4 = fmaxf(h4, 0.f);
    float p = h4 * w_uv3[jj];
#pragma unroll
    for (int m = 1; m < 16; m <<= 1) p += __shfl_xor(p, m);
    const float score = p + b_uv3[0];

    if (lane == 0) {
        out_score[row] = score;
        ws_d2[row] = dmin2;
        ws_c[row] = cval;
    }
}

// ---------- final combine: single block, global min/max + outputs ----------
__global__ __launch_bounds__(1024) void combine(
    const float* __restrict__ ws_d2, const float* __restrict__ ws_c,
    float* __restrict__ out) {
    const int tid = threadIdx.x;
    __shared__ float red[4][16];

    float ld2[8], lc[8];
    float dmin = BIGF, dmax = -BIGF, cmin = BIGF, cmax = -BIGF;
#pragma unroll
    for (int i = 0; i < 8; ++i) {
        const int b = tid * 8 + i;  // 1024 * 8 == 8192
        ld2[i] = ws_d2[b];
        lc[i] = ws_c[b];
        dmin = fminf(dmin, ld2[i]);
        dmax = fmaxf(dmax, ld2[i]);
        cmin = fminf(cmin, lc[i]);
        cmax = fmaxf(cmax, lc[i]);
    }
#pragma unroll
    for (int m = 1; m < 64; m <<= 1) {
        dmin = fminf(dmin, __shfl_xor(dmin, m));
        dmax = fmaxf(dmax, __shfl_xor(dmax, m));
        cmin = fminf(cmin, __shfl_xor(cmin, m));
        cmax = fmaxf(cmax, __shfl_xor(cmax, m));
    }
    const int wid = tid >> 6;
    const int lane = tid & 63;
    if (lane == 0) {
        red[0][wid] = dmin;
        red[1][wid] = dmax;
        red[2][wid] = cmin;
        red[3][wid] = cmax;
    }
    __syncthreads();
    dmin = red[0][0]; dmax = red[1][0]; cmin = red[2][0]; cmax = red[3][0];
#pragma unroll
    for (int i = 1; i < 16; ++i) {
        dmin = fminf(dmin, red[0][i]);
        dmax = fmaxf(dmax, red[1][i]);
        cmin = fminf(cmin, red[2][i]);
        cmax = fmaxf(cmax, red[3][i]);
    }
    const float dlo = sqrtf(dmin);
    const float dhi = sqrtf(dmax);
    const float inv_d = 1.f / (dhi - dlo);
    const float inv_c = 1.f / (cmax - cmin);
#pragma unroll
    for (int i = 0; i < 8; ++i) {
        const int b = tid * 8 + i;
        const float t = (sqrtf(ld2[i]) - dlo) * inv_d;
        const float unexp = 6.f * t * expf(-6.f * t);
        out[b] += unexp * (lc[i] - cmin) * inv_c;
    }
}

extern "C" void kernel_launch(void* const* d_in, const int* in_sizes, int n_in,
                              void* d_out, int out_size, void* d_ws, size_t ws_size,
                              hipStream_t stream) {
    const float* v_embed = (const float*)d_in[0];
    const float* u1 = (const float*)d_in[1];
    const float* u2 = (const float*)d_in[2];
    const float* u3 = (const float*)d_in[3];
    const float* u4 = (const float*)d_in[4];
    const float* ev = (const float*)d_in[5];
    const float* w_ur1 = (const float*)d_in[6];
    const float* b_ur1 = (const float*)d_in[7];
    const float* w_ur2 = (const float*)d_in[8];
    const float* b_ur2 = (const float*)d_in[9];
    const float* w_vr1 = (const float*)d_in[10];
    const float* b_vr1 = (const float*)d_in[11];
    const float* w_vr2 = (const float*)d_in[12];
    const float* b_vr2 = (const float*)d_in[13];
    const float* w_uv1 = (const float*)d_in[14];
    const float* b_uv1 = (const float*)d_in[15];
    const float* w_uv2 = (const float*)d_in[16];
    const float* b_uv2 = (const float*)d_in[17];
    const float* w_uv3 = (const float*)d_in[18];
    const float* b_uv3 = (const float*)d_in[19];
    const int* nodes_v = (const int*)d_in[20];
    const int* nbr_idx = (const int*)d_in[21];
    const int* nbr_len = (const int*)d_in[22];
    const float* bn1_g = (const float*)d_in[23];
    const float* bn1_b = (const float*)d_in[24];
    const float* bn1_m = (const float*)d_in[25];
    const float* bn1_v = (const float*)d_in[26];
    const float* bn2_g = (const float*)d_in[27];
    const float* bn2_b = (const float*)d_in[28];
    const float* bn2_m = (const float*)d_in[29];
    const float* bn2_v = (const float*)d_in[30];
    const float* bn3_g = (const float*)d_in[31];
    const float* bn3_b = (const float*)d_in[32];
    const float* bn3_m = (const float*)d_in[33];
    const float* bn3_v = (const float*)d_in[34];
    const float* bn4_g = (const float*)d_in[35];
    const float* bn4_b = (const float*)d_in[36];
    const float* bn4_m = (const float*)d_in[37];
    const float* bn4_v = (const float*)d_in[38];

    float* out = (float*)d_out;
    float* wsf = (float*)d_ws;
    float* ws_d2 = wsf;
    float* ws_c = wsf + NROWS;

    hipLaunchKernelGGL(fused_rows, dim3(NROWS / 4), dim3(256), 0, stream,
                       v_embed, u1, u2, u3, u4, ev,
                       w_ur1, b_ur1, w_ur2, b_ur2, w_vr1, b_vr1, w_vr2, b_vr2,
                       w_uv1, b_uv1, w_uv2, b_uv2, w_uv3, b_uv3,
                       bn1_g, bn1_b, bn1_m, bn1_v,
                       bn2_g, bn2_b, bn2_m, bn2_v,
                       bn3_g, bn3_b, bn3_m, bn3_v,
                       bn4_g, bn4_b, bn4_m, bn4_v,
                       nodes_v, nbr_idx, nbr_len,
                       out, ws_d2, ws_c);
    hipLaunchKernelGGL(combine, dim3(1), dim3(1024), 0, stream,
                       ws_d2, ws_c, out);
}